// Round 8
// baseline (204.840 us; speedup 1.0000x reference)
//
#include <hip/hip_runtime.h>

// Shapes (fixed): B=2, T=2048, E=1024, H=16, Hkv=4, D=64, G=4, W=1024
// Scores bounded: q rmsnormed (|q|=8) * 0.125 * k rmsnormed (|k|=8) => |s| <= 8.
// log2(e) folded into q; softmax uses exp2 with FIXED max M = 8*log2(e).
// Attention computes S^T = K·Q^T so P^T (C-layout) is directly the B-operand
// of mfma_f32_16x16x16f16 -> no P LDS round-trip.
// attn: 64-key stages, double-buffered LDS, single barrier per stage.

typedef float f32x4 __attribute__((ext_vector_type(4)));
typedef short s16x8 __attribute__((ext_vector_type(8)));
typedef short s16x4 __attribute__((ext_vector_type(4)));
typedef _Float16 f16x4 __attribute__((ext_vector_type(4)));

__device__ __forceinline__ unsigned short f2bf(float f) {
  unsigned u = __float_as_uint(f);
  u += 0x7fffu + ((u >> 16) & 1u);   // RNE
  return (unsigned short)(u >> 16);
}
__device__ __forceinline__ unsigned short h16(float f) {
  _Float16 h = (_Float16)f;
  return __builtin_bit_cast(unsigned short, h);
}

__device__ __forceinline__ float fexp2(float x) {
#if __has_builtin(__builtin_amdgcn_exp2f)
  return __builtin_amdgcn_exp2f(x);
#else
  return __expf(x * 0.69314718f);
#endif
}

// async global->LDS, 16B per lane; LDS dest = wave-uniform base + lane*16
__device__ __forceinline__ void gl2lds16(const unsigned short* g, unsigned short* l) {
  __builtin_amdgcn_global_load_lds((const __attribute__((address_space(1))) unsigned int*)g,
                                   (__attribute__((address_space(3))) unsigned int*)l, 16, 0, 0);
}

// ---------------- all fp32 -> bf16 converts in one launch ----------------
__global__ __launch_bounds__(256) void cvt_all(
    const float* __restrict__ x, const float* __restrict__ wq, const float* __restrict__ wk,
    const float* __restrict__ wv, const float* __restrict__ wp,
    unsigned short* __restrict__ xb, unsigned short* __restrict__ wqkv,
    unsigned short* __restrict__ wpj) {
  int i = blockIdx.x * 256 + threadIdx.x;  // float4 index, total 1703936
  const float* s;
  unsigned short* d;
  if (i < 1048576) { s = x; d = xb; }
  else if (i < 1310720) { i -= 1048576; s = wq; d = wqkv; }
  else if (i < 1376256) { i -= 1310720; s = wk; d = wqkv + 1048576; }
  else if (i < 1441792) { i -= 1376256; s = wv; d = wqkv + 1310720; }
  else { i -= 1441792; s = wp; d = wpj; }
  float4 v = ((const float4*)s)[i];
  ushort4 o;
  o.x = f2bf(v.x); o.y = f2bf(v.y); o.z = f2bf(v.z); o.w = f2bf(v.w);
  ((ushort4*)d)[i] = o;
}

// ---------------- gate[t][h] = 2*sigmoid(x[t,:32] . Wgate[h]) ----------------
__global__ __launch_bounds__(256) void gate_kernel(const float* __restrict__ x,
                                                   const float* __restrict__ wgate,
                                                   float* __restrict__ gatep) {
  int i = blockIdx.x * 256 + threadIdx.x;  // i = bt*4 + h, total 16384
  int bt = i >> 2, h = i & 3;
  const float4* xp = (const float4*)(x + (size_t)bt * 1024);
  const float4* wp = (const float4*)(wgate + h * 32);
  float s = 0.f;
#pragma unroll
  for (int j = 0; j < 8; ++j) {
    float4 a = xp[j], b = wp[j];
    s += a.x * b.x + a.y * b.y + a.z * b.z + a.w * b.w;
  }
  gatep[i] = 2.f / (1.f + __expf(-s));
}

// ---- fused QKV GEMM (64x128 tile, 768 blocks = 3/CU) + RoPE/RMSNorm/gate-ve epilogue ----
// A = xb (4096x1024), B = wqkv (1536x1024). Col-tile bn: 0-7 q, 8-9 k, 10-11 v.
__global__ __launch_bounds__(256) void gemm_qkv(
    const unsigned short* __restrict__ A, const unsigned short* __restrict__ B,
    const float* __restrict__ cosp, const float* __restrict__ sinp,
    const float* __restrict__ gatep, const float* __restrict__ ve,
    unsigned short* __restrict__ q_r, unsigned short* __restrict__ k_r,
    unsigned short* __restrict__ v_r) {
  __shared__ unsigned short As[64 * 32];
  __shared__ unsigned short Bs[128 * 32];
  const int K = 1024;
  int bn = blockIdx.x, bm = blockIdx.y;
  int t = threadIdx.x;
  int w = t >> 6, lane = t & 63;
  int c = lane & 15, g = lane >> 4;
  int wm = w >> 1, wn = w & 1;

  f32x4 acc[2][4];
#pragma unroll
  for (int i = 0; i < 2; ++i)
#pragma unroll
    for (int j = 0; j < 4; ++j) acc[i][j] = (f32x4){0.f, 0.f, 0.f, 0.f};

  const unsigned short* Ab = A + (size_t)(bm * 64) * K;
  const unsigned short* Bb = B + (size_t)(bn * 128) * K;
  int srow = lane >> 2;
  int scol = (lane & 3) * 8;

  for (int k0 = 0; k0 < K; k0 += 32) {
    gl2lds16(Ab + (size_t)(w * 16 + srow) * K + k0 + scol, As + w * 512);
    gl2lds16(Bb + (size_t)(w * 16 + srow) * K + k0 + scol, Bs + w * 512);
    gl2lds16(Bb + (size_t)(64 + w * 16 + srow) * K + k0 + scol, Bs + 2048 + w * 512);
    __syncthreads();
    s16x8 af[2], bf[4];
#pragma unroll
    for (int mt = 0; mt < 2; ++mt)
      af[mt] = *(const s16x8*)(As + (wm * 32 + mt * 16 + c) * 32 + g * 8);
#pragma unroll
    for (int nt = 0; nt < 4; ++nt)
      bf[nt] = *(const s16x8*)(Bs + (wn * 64 + nt * 16 + c) * 32 + g * 8);
#pragma unroll
    for (int mt = 0; mt < 2; ++mt)
#pragma unroll
      for (int nt = 0; nt < 4; ++nt)
        acc[mt][nt] = __builtin_amdgcn_mfma_f32_16x16x32_bf16(af[mt], bf[nt], acc[mt][nt], 0, 0, 0);
    __syncthreads();
  }

  // epilogue: lane (c,g) reg r of tile (mt,nt): row = bm*64+wm*32+mt*16+g*4+r,
  // within-head d = nt*16 + c (a head = 64 cols = one wn half-tile)
  const float QSCL = 0.125f * 1.44269504f;
#pragma unroll
  for (int mt = 0; mt < 2; ++mt) {
#pragma unroll
    for (int r = 0; r < 4; ++r) {
      int row = bm * 64 + wm * 32 + mt * 16 + g * 4 + r;
      int b = row >> 11, tt = row & 2047;
      float v0 = acc[mt][0][r], v1 = acc[mt][1][r], v2 = acc[mt][2][r], v3 = acc[mt][3][r];
      if (bn < 10) {  // q or k: rope + rmsnorm
        float cs0 = cosp[tt * 32 + c], sn0 = sinp[tt * 32 + c];
        float cs1 = cosp[tt * 32 + 16 + c], sn1 = sinp[tt * 32 + 16 + c];
        float r0 = v0 * cs0 + v2 * sn0;   // d = c
        float r1 = v1 * cs1 + v3 * sn1;   // d = 16+c
        float r2 = v2 * cs0 - v0 * sn0;   // d = 32+c
        float r3 = v3 * cs1 - v1 * sn1;   // d = 48+c
        float ss = r0 * r0 + r1 * r1 + r2 * r2 + r3 * r3;
        ss += __shfl_xor(ss, 1);
        ss += __shfl_xor(ss, 2);
        ss += __shfl_xor(ss, 4);
        ss += __shfl_xor(ss, 8);
        float sc = rsqrtf(ss * (1.0f / 64.0f) + 1.1920929e-07f);
        if (bn < 8) {
          int h = bn * 2 + wn;
          unsigned short* qp = q_r + ((size_t)(b * 16 + h) * 2048 + tt) * 64;
          float s2 = sc * QSCL;
          qp[c] = f2bf(r0 * s2);
          qp[16 + c] = f2bf(r1 * s2);
          qp[32 + c] = f2bf(r2 * s2);
          qp[48 + c] = f2bf(r3 * s2);
        } else {
          int h = (bn - 8) * 2 + wn;
          unsigned short* kp = k_r + ((size_t)(b * 4 + h) * 2048 + tt) * 64;
          kp[c] = f2bf(r0 * sc);
          kp[16 + c] = f2bf(r1 * sc);
          kp[32 + c] = f2bf(r2 * sc);
          kp[48 + c] = f2bf(r3 * sc);
        }
      } else {  // v: + gate * ve, store fp16
        int h = (bn - 10) * 2 + wn;
        float gate = gatep[row * 4 + h];
        const float* vep = ve + (size_t)row * 256 + h * 64;
        unsigned short* vp = v_r + ((size_t)(b * 4 + h) * 2048 + tt) * 64;
        vp[c] = h16(v0 + gate * vep[c]);
        vp[16 + c] = h16(v1 + gate * vep[16 + c]);
        vp[32 + c] = h16(v2 + gate * vep[32 + c]);
        vp[48 + c] = h16(v3 + gate * vep[48 + c]);
      }
    }
  }
}

// ---------------- bf16 GEMM, 64x128 tile: C = A(MxK) @ B(NxK)^T ----------------
__global__ __launch_bounds__(256) void gemm_bf16_64(
    const unsigned short* __restrict__ A, const unsigned short* __restrict__ B,
    float* __restrict__ C, int K, int ldc) {
  __shared__ unsigned short As[64 * 32];
  __shared__ unsigned short Bs[128 * 32];
  int bn = blockIdx.x, bm = blockIdx.y;
  int t = threadIdx.x;
  int w = t >> 6, lane = t & 63;
  int c = lane & 15, g = lane >> 4;
  int wm = w >> 1, wn = w & 1;

  f32x4 acc[2][4];
#pragma unroll
  for (int i = 0; i < 2; ++i)
#pragma unroll
    for (int j = 0; j < 4; ++j) acc[i][j] = (f32x4){0.f, 0.f, 0.f, 0.f};

  const unsigned short* Ab = A + (size_t)(bm * 64) * K;
  const unsigned short* Bb = B + (size_t)(bn * 128) * K;
  int srow = lane >> 2;
  int scol = (lane & 3) * 8;

  for (int k0 = 0; k0 < K; k0 += 32) {
    gl2lds16(Ab + (size_t)(w * 16 + srow) * K + k0 + scol, As + w * 512);
    gl2lds16(Bb + (size_t)(w * 16 + srow) * K + k0 + scol, Bs + w * 512);
    gl2lds16(Bb + (size_t)(64 + w * 16 + srow) * K + k0 + scol, Bs + 2048 + w * 512);
    __syncthreads();
    s16x8 af[2], bf[4];
#pragma unroll
    for (int mt = 0; mt < 2; ++mt)
      af[mt] = *(const s16x8*)(As + (wm * 32 + mt * 16 + c) * 32 + g * 8);
#pragma unroll
    for (int nt = 0; nt < 4; ++nt)
      bf[nt] = *(const s16x8*)(Bs + (wn * 64 + nt * 16 + c) * 32 + g * 8);
#pragma unroll
    for (int mt = 0; mt < 2; ++mt)
#pragma unroll
      for (int nt = 0; nt < 4; ++nt)
        acc[mt][nt] = __builtin_amdgcn_mfma_f32_16x16x32_bf16(af[mt], bf[nt], acc[mt][nt], 0, 0, 0);
    __syncthreads();
  }
#pragma unroll
  for (int mt = 0; mt < 2; ++mt)
#pragma unroll
    for (int nt = 0; nt < 4; ++nt)
#pragma unroll
      for (int r = 0; r < 4; ++r) {
        int rowg = bm * 64 + wm * 32 + mt * 16 + g * 4 + r;
        int colg = bn * 128 + wn * 64 + nt * 16 + c;
        C[(size_t)rowg * ldc + colg] = acc[mt][nt][r];
      }
}

// ---- V transpose to tiled layout: v_r[8][2048][64] -> v_p2[8][64 tiles][64 d][32 keys] ----
__global__ __launch_bounds__(256) void transpose_v(const unsigned short* __restrict__ v_r,
                                                   unsigned short* __restrict__ v_p2) {
  __shared__ unsigned short tile[64][72];
  int blk = blockIdx.x;
  int s = blk >> 5;
  int t0 = (blk & 31) * 64;
  int tt = threadIdx.x;
  int rcol = (tt & 7) * 8;
  int rrow = tt >> 3;
#pragma unroll
  for (int i = 0; i < 2; ++i) {
    int row = rrow + i * 32;
    *(s16x8*)&tile[row][rcol] = *(const s16x8*)(v_r + ((size_t)s * 2048 + t0 + row) * 64 + rcol);
  }
  __syncthreads();
#pragma unroll
  for (int i = 0; i < 2; ++i) {
    int idx = tt + i * 256;
    int ht = idx >> 8;
    int d = (idx >> 2) & 63;
    int e8 = (idx & 3) * 8;
    s16x8 o;
#pragma unroll
    for (int j = 0; j < 8; ++j) o[j] = tile[ht * 32 + e8 + j][d];
    *(s16x8*)(v_p2 + (size_t)s * 131072 + ((size_t)((t0 >> 5) + ht)) * 2048 + d * 32 + e8) = o;
  }
}

// ---------------- flash attention: S^T form, 64-key double-buffered stages ----------------
__global__ __launch_bounds__(256) void attn_kernel(
    const unsigned short* __restrict__ q_r, const unsigned short* __restrict__ k_r,
    const unsigned short* __restrict__ v_p2, unsigned short* __restrict__ y_b,
    const int* __restrict__ wptr) {
  const int W = *wptr;
  const int bid = blockIdx.x;
  const int qt = bid & 31, h = (bid >> 5) & 15, b = bid >> 9;
  const int tid = threadIdx.x;
  const int w = tid >> 6, lane = tid & 63, c = lane & 15, g = lane >> 4;
  const int r0b = qt * 64;
  const int r0w = r0b + w * 16;
  const int hkv = h >> 2;
  const float M = 11.5415603f;  // 8 * log2(e)

  __shared__ unsigned short Ks[2][64 * 68];  // [buf][key][d+pad]
  __shared__ unsigned short Vs[2][64 * 72];  // [buf][d][key+pad]

  const unsigned short* kbase = k_r + (size_t)(b * 4 + hkv) * 131072;
  const unsigned short* vbase = v_p2 + (size_t)(b * 4 + hkv) * 131072;
  const unsigned short* qbase = q_r + ((size_t)(b * 16 + h) * 2048 + r0w) * 64;

  // Q as B-operand of 16x16x32: B[n=c][k=g*8+j]
  s16x8 q_lo = *(const s16x8*)(qbase + c * 64 + g * 8);
  s16x8 q_hi = *(const s16x8*)(qbase + c * 64 + 32 + g * 8);

  int kt0w = r0w - W; if (kt0w < 0) kt0w = 0;
  const int ktEw = r0w + 16;
  int KT0 = r0b - W; if (KT0 < 0) KT0 = 0;
  KT0 &= ~63;
  const int KTE = r0b + 64;
  const int nst = (KTE - KT0) >> 6;

  // staging thread mapping (32B per thread for each of K and V)
  const int krow = tid >> 2;            // key 0..63
  const int kcol = (tid & 3) * 16;      // d 0,16,32,48
  const int vtile = tid >> 7;           // 32-key tile 0/1
  const int vd = (tid >> 1) & 63;       // d row
  const int vk0 = (tid & 1) * 16;       // key group

  float l_part = 0.f;
  f32x4 acc[4];
#pragma unroll
  for (int dt = 0; dt < 4; ++dt) acc[dt] = (f32x4){0.f, 0.f, 0.f, 0.f};

  // prefetch stage 0
  s16x8 pk0, pk1, pv0, pv1;
  {
    const unsigned short* kg = kbase + (size_t)(KT0 + krow) * 64 + kcol;
    pk0 = *(const s16x8*)kg; pk1 = *(const s16x8*)(kg + 8);
    const unsigned short* vg = vbase + (size_t)((KT0 >> 5) + vtile) * 2048 + vd * 32 + vk0;
    pv0 = *(const s16x8*)vg; pv1 = *(const s16x8*)(vg + 8);
  }

  for (int s = 0; s < nst; ++s) {
    const int kt = KT0 + (s << 6);
    const int nkt = (s + 1 < nst) ? kt + 64 : kt;  // dup load last iter (in-bounds)
    s16x8 nk0, nk1, nv0, nv1;
    {
      const unsigned short* kg = kbase + (size_t)(nkt + krow) * 64 + kcol;
      nk0 = *(const s16x8*)kg; nk1 = *(const s16x8*)(kg + 8);
      const unsigned short* vg = vbase + (size_t)((nkt >> 5) + vtile) * 2048 + vd * 32 + vk0;
      nv0 = *(const s16x8*)vg; nv1 = *(const s16x8*)(vg + 8);
    }

    // stage s (regs prefetched last iter) into buf s&1; single barrier (dbuf-safe)
    unsigned short* kd = &Ks[s & 1][krow * 68 + kcol];
    *(s16x8*)kd = pk0; *(s16x8*)(kd + 8) = pk1;
    unsigned short* vdp = &Vs[s & 1][vd * 72 + vtile * 32 + vk0];
    *(s16x8*)vdp = pv0; *(s16x8*)(vdp + 8) = pv1;
    __syncthreads();

    if (kt + 64 > kt0w && kt < ktEw) {  // wave-uniform strip overlap
      const unsigned short* Kb = &Ks[s & 1][0];
      const unsigned short* Vb = &Vs[s & 1][0];
#pragma unroll
      for (int ks = 0; ks < 4; ++ks) {
        const int kb = kt + ks * 16;
        if (kb >= ktEw || kb + 16 <= kt0w) continue;  // subtile outside window
        // K frag as A-operand: A[m=c -> key kb+c][k=g*8+j -> d]
        const unsigned short* kr = Kb + (ks * 16 + c) * 68 + g * 8;
        s16x4 a0 = *(const s16x4*)(kr);
        s16x4 a1 = *(const s16x4*)(kr + 4);
        s16x4 a2 = *(const s16x4*)(kr + 32);
        s16x4 a3 = *(const s16x4*)(kr + 36);
        s16x8 klo = __builtin_shufflevector(a0, a1, 0, 1, 2, 3, 4, 5, 6, 7);
        s16x8 khi = __builtin_shufflevector(a2, a3, 0, 1, 2, 3, 4, 5, 6, 7);

        f32x4 S = (f32x4){0.f, 0.f, 0.f, 0.f};
        S = __builtin_amdgcn_mfma_f32_16x16x32_bf16(klo, q_lo, S, 0, 0, 0);
        S = __builtin_amdgcn_mfma_f32_16x16x32_bf16(khi, q_hi, S, 0, 0, 0);

        const bool edge = (kb < kt0w + 16) || (kb + 16 > r0w);
        const int qrow = r0w + c;
        f16x4 P;
#pragma unroll
        for (int r = 0; r < 4; ++r) {
          float p = fexp2(S[r] - M);
          if (edge) {
            int ki = kb + g * 4 + r;
            if (!(ki <= qrow && ki >= qrow - W)) p = 0.f;
          }
          l_part += p;
          P[r] = (_Float16)p;
        }
#pragma unroll
        for (int dt = 0; dt < 4; ++dt) {
          f16x4 va = *(const f16x4*)(Vb + (dt * 16 + c) * 72 + ks * 16 + g * 4);
          acc[dt] = __builtin_amdgcn_mfma_f32_16x16x16f16(va, P, acc[dt], 0, 0, 0);
        }
      }
    }
    pk0 = nk0; pk1 = nk1; pv0 = nv0; pv1 = nv1;
  }

  // l reduce across g-groups (lanes 16/32 apart hold other key subsets of same qrow)
  float l = l_part;
  l += __shfl_xor(l, 16);
  l += __shfl_xor(l, 32);
  float inv = 1.0f / l;

  // lane (c,g) holds O[qrow=r0w+c][d = dt*16 + g*4 + r]
  unsigned short* ob = y_b + ((size_t)(b * 2048 + r0w + c) * 16 + h) * 64 + g * 4;
#pragma unroll
  for (int dt = 0; dt < 4; ++dt) {
    ushort4 o;
    o.x = f2bf(acc[dt][0] * inv);
    o.y = f2bf(acc[dt][1] * inv);
    o.z = f2bf(acc[dt][2] * inv);
    o.w = f2bf(acc[dt][3] * inv);
    *(ushort4*)(ob + dt * 16) = o;
  }
}

extern "C" void kernel_launch(void* const* d_in, const int* in_sizes, int n_in,
                              void* d_out, int out_size, void* d_ws, size_t ws_size,
                              hipStream_t stream) {
  const float* x = (const float*)d_in[0];
  const float* ve = (const float*)d_in[1];
  const float* cosp = (const float*)d_in[2];
  const float* sinp = (const float*)d_in[3];
  const float* Wq = (const float*)d_in[4];
  const float* Wk = (const float*)d_in[5];
  const float* Wv = (const float*)d_in[6];
  const float* Wproj = (const float*)d_in[7];
  const float* Wgate = (const float*)d_in[8];
  const int* wptr = (const int*)d_in[9];

  unsigned short* xb = (unsigned short*)d_ws;        // 4096x1024 bf16
  unsigned short* wqkv = xb + 4194304;               // 1536x1024 bf16
  unsigned short* wpj = wqkv + 1572864;              // 1024x1024 bf16
  unsigned short* q_r = wpj + 1048576;               // [B,H,T,D] bf16
  unsigned short* k_r = q_r + 4194304;               // [B,Hkv,T,D] bf16
  unsigned short* v_r = k_r + 1048576;               // [B,Hkv,T,D] fp16
  unsigned short* y_b = v_r + 1048576;               // [B,T,H,D] bf16
  unsigned short* vp2 = y_b + 4194304;               // [B*Hkv][T/32][64][32] fp16 (2 MB)
  float* gatep = (float*)(vp2 + 1048576);            // [4096][4] fp32 (64 KB)

  cvt_all<<<6656, 256, 0, stream>>>(x, Wq, Wk, Wv, Wproj, xb, wqkv, wpj);
  gate_kernel<<<64, 256, 0, stream>>>(x, Wgate, gatep);
  gemm_qkv<<<dim3(12, 64), 256, 0, stream>>>(xb, wqkv, cosp, sinp, gatep, ve, q_r, k_r, v_r);
  transpose_v<<<256, 256, 0, stream>>>(v_r, vp2);
  attn_kernel<<<1024, 256, 0, stream>>>(q_r, k_r, vp2, y_b, wptr);
  gemm_bf16_64<<<dim3(8, 64), 256, 0, stream>>>(y_b, wpj, (float*)d_out, 1024, 1024);
}

// Round 9
// 185.769 us; speedup vs baseline: 1.1027x; 1.1027x over previous
//
#include <hip/hip_runtime.h>

// Shapes (fixed): B=2, T=2048, E=1024, H=16, Hkv=4, D=64, G=4, W=1024
// Scores bounded: q rmsnormed (|q|=8) * 0.125 * k rmsnormed (|k|=8) => |s| <= 8.
// log2(e) folded into q; softmax uses exp2 with FIXED max M = 8*log2(e).
// Attention (R6 structure): S^T = K·Q^T so P^T (C-layout) is directly the
// B-operand of mfma_f32_16x16x16f16 -> P never leaves registers.
// gemm_qkv: 64x128 tile (768 blocks = 3/CU); q/k epilogue transposes each
// wave's 32x64 head-tile through wave-private LDS -> coalesced b128 stores.

typedef float f32x4 __attribute__((ext_vector_type(4)));
typedef short s16x8 __attribute__((ext_vector_type(8)));
typedef short s16x4 __attribute__((ext_vector_type(4)));
typedef _Float16 f16x4 __attribute__((ext_vector_type(4)));

__device__ __forceinline__ unsigned short f2bf(float f) {
  unsigned u = __float_as_uint(f);
  u += 0x7fffu + ((u >> 16) & 1u);   // RNE
  return (unsigned short)(u >> 16);
}
__device__ __forceinline__ unsigned short h16(float f) {
  _Float16 h = (_Float16)f;
  return __builtin_bit_cast(unsigned short, h);
}

__device__ __forceinline__ float fexp2(float x) {
#if __has_builtin(__builtin_amdgcn_exp2f)
  return __builtin_amdgcn_exp2f(x);
#else
  return __expf(x * 0.69314718f);
#endif
}

// async global->LDS, 16B per lane; LDS dest = wave-uniform base + lane*16
__device__ __forceinline__ void gl2lds16(const unsigned short* g, unsigned short* l) {
  __builtin_amdgcn_global_load_lds((const __attribute__((address_space(1))) unsigned int*)g,
                                   (__attribute__((address_space(3))) unsigned int*)l, 16, 0, 0);
}

// ---------------- fp32->bf16 converts + gate, one launch ----------------
__global__ __launch_bounds__(256) void cvt_gate(
    const float* __restrict__ x, const float* __restrict__ wq, const float* __restrict__ wk,
    const float* __restrict__ wv, const float* __restrict__ wp, const float* __restrict__ wgate,
    unsigned short* __restrict__ xb, unsigned short* __restrict__ wqkv,
    unsigned short* __restrict__ wpj, float* __restrict__ gatep) {
  int blk = blockIdx.x;
  if (blk < 6656) {
    int i = blk * 256 + threadIdx.x;  // float4 index, total 1703936
    const float* s;
    unsigned short* d;
    if (i < 1048576) { s = x; d = xb; }
    else if (i < 1310720) { i -= 1048576; s = wq; d = wqkv; }
    else if (i < 1376256) { i -= 1310720; s = wk; d = wqkv + 1048576; }
    else if (i < 1441792) { i -= 1376256; s = wv; d = wqkv + 1310720; }
    else { i -= 1441792; s = wp; d = wpj; }
    float4 v = ((const float4*)s)[i];
    ushort4 o;
    o.x = f2bf(v.x); o.y = f2bf(v.y); o.z = f2bf(v.z); o.w = f2bf(v.w);
    ((ushort4*)d)[i] = o;
  } else {
    int i = (blk - 6656) * 256 + threadIdx.x;  // i = bt*4 + h, total 16384
    int bt = i >> 2, h = i & 3;
    const float4* xp = (const float4*)(x + (size_t)bt * 1024);
    const float4* wpt = (const float4*)(wgate + h * 32);
    float s = 0.f;
#pragma unroll
    for (int j = 0; j < 8; ++j) {
      float4 a = xp[j], b = wpt[j];
      s += a.x * b.x + a.y * b.y + a.z * b.z + a.w * b.w;
    }
    gatep[i] = 2.f / (1.f + __expf(-s));
  }
}

// ---- fused QKV GEMM (64x128 tile, 768 blocks = 3/CU) + RoPE/RMSNorm/gate-ve epilogue ----
// A = xb (4096x1024), B = wqkv (1536x1024). Col-tile bn: 0-7 q, 8-9 k, 10-11 v.
__global__ __launch_bounds__(256) void gemm_qkv(
    const unsigned short* __restrict__ A, const unsigned short* __restrict__ B,
    const float* __restrict__ cosp, const float* __restrict__ sinp,
    const float* __restrict__ gatep, const float* __restrict__ ve,
    unsigned short* __restrict__ q_r, unsigned short* __restrict__ k_r,
    unsigned short* __restrict__ v_r) {
  __shared__ unsigned short As[64 * 32];
  __shared__ unsigned short Bs[128 * 32];
  __shared__ unsigned short epi[4][32 * 68];  // per-wave transpose buffer (q/k epilogue)
  const int K = 1024;
  int bn = blockIdx.x, bm = blockIdx.y;
  int t = threadIdx.x;
  int w = t >> 6, lane = t & 63;
  int c = lane & 15, g = lane >> 4;
  int wm = w >> 1, wn = w & 1;

  f32x4 acc[2][4];
#pragma unroll
  for (int i = 0; i < 2; ++i)
#pragma unroll
    for (int j = 0; j < 4; ++j) acc[i][j] = (f32x4){0.f, 0.f, 0.f, 0.f};

  const unsigned short* Ab = A + (size_t)(bm * 64) * K;
  const unsigned short* Bb = B + (size_t)(bn * 128) * K;
  int srow = lane >> 2;
  int scol = (lane & 3) * 8;

  for (int k0 = 0; k0 < K; k0 += 32) {
    gl2lds16(Ab + (size_t)(w * 16 + srow) * K + k0 + scol, As + w * 512);
    gl2lds16(Bb + (size_t)(w * 16 + srow) * K + k0 + scol, Bs + w * 512);
    gl2lds16(Bb + (size_t)(64 + w * 16 + srow) * K + k0 + scol, Bs + 2048 + w * 512);
    __syncthreads();
    s16x8 af[2], bf[4];
#pragma unroll
    for (int mt = 0; mt < 2; ++mt)
      af[mt] = *(const s16x8*)(As + (wm * 32 + mt * 16 + c) * 32 + g * 8);
#pragma unroll
    for (int nt = 0; nt < 4; ++nt)
      bf[nt] = *(const s16x8*)(Bs + (wn * 64 + nt * 16 + c) * 32 + g * 8);
#pragma unroll
    for (int mt = 0; mt < 2; ++mt)
#pragma unroll
      for (int nt = 0; nt < 4; ++nt)
        acc[mt][nt] = __builtin_amdgcn_mfma_f32_16x16x32_bf16(af[mt], bf[nt], acc[mt][nt], 0, 0, 0);
    __syncthreads();
  }

  // epilogue: lane (c,g) reg r of tile (mt,nt): local row = wm*32+mt*16+g*4+r,
  // within-head d = nt*16 + c (head = 64 cols = wn half-tile)
  const float QSCL = 0.125f * 1.44269504f;
  if (bn < 10) {  // q or k: rope + rmsnorm, then LDS transpose -> coalesced b128 stores
    unsigned short* eb = epi[w];
#pragma unroll
    for (int mt = 0; mt < 2; ++mt) {
#pragma unroll
      for (int r = 0; r < 4; ++r) {
        int lrow = mt * 16 + g * 4 + r;
        int rowg = bm * 64 + wm * 32 + lrow;
        int tt = rowg & 2047;
        float v0 = acc[mt][0][r], v1 = acc[mt][1][r], v2 = acc[mt][2][r], v3 = acc[mt][3][r];
        float cs0 = cosp[tt * 32 + c], sn0 = sinp[tt * 32 + c];
        float cs1 = cosp[tt * 32 + 16 + c], sn1 = sinp[tt * 32 + 16 + c];
        float r0 = v0 * cs0 + v2 * sn0;   // d = c
        float r1 = v1 * cs1 + v3 * sn1;   // d = 16+c
        float r2 = v2 * cs0 - v0 * sn0;   // d = 32+c
        float r3 = v3 * cs1 - v1 * sn1;   // d = 48+c
        float ss = r0 * r0 + r1 * r1 + r2 * r2 + r3 * r3;
        ss += __shfl_xor(ss, 1);
        ss += __shfl_xor(ss, 2);
        ss += __shfl_xor(ss, 4);
        ss += __shfl_xor(ss, 8);
        float sc = rsqrtf(ss * (1.0f / 64.0f) + 1.1920929e-07f);
        if (bn < 8) sc *= QSCL;
        eb[lrow * 68 + c] = f2bf(r0 * sc);
        eb[lrow * 68 + 16 + c] = f2bf(r1 * sc);
        eb[lrow * 68 + 32 + c] = f2bf(r2 * sc);
        eb[lrow * 68 + 48 + c] = f2bf(r3 * sc);
      }
    }
    asm volatile("s_waitcnt lgkmcnt(0)" ::: "memory");  // wave-private: no barrier needed
#pragma unroll
    for (int j = 0; j < 4; ++j) {
      int idx = lane * 4 + j;     // 256 chunks: 32 rows x 8 chunks
      int lrow = idx >> 3;
      int ck = idx & 7;
      s16x8 val = *(const s16x8*)(eb + lrow * 68 + ck * 8);
      int rowg = bm * 64 + wm * 32 + lrow;
      int b = rowg >> 11, tt = rowg & 2047;
      unsigned short* dst;
      if (bn < 8) dst = q_r + ((size_t)(b * 16 + bn * 2 + wn) * 2048 + tt) * 64 + ck * 8;
      else dst = k_r + ((size_t)(b * 4 + (bn - 8) * 2 + wn) * 2048 + tt) * 64 + ck * 8;
      *(s16x8*)dst = val;
    }
  } else {  // v: + gate * ve, store fp16 (scattered; only 2/12 of blocks)
#pragma unroll
    for (int mt = 0; mt < 2; ++mt) {
#pragma unroll
      for (int r = 0; r < 4; ++r) {
        int rowg = bm * 64 + wm * 32 + mt * 16 + g * 4 + r;
        int b = rowg >> 11, tt = rowg & 2047;
        int h = (bn - 10) * 2 + wn;
        float gate = gatep[rowg * 4 + h];
        const float* vep = ve + (size_t)rowg * 256 + h * 64;
        unsigned short* vp = v_r + ((size_t)(b * 4 + h) * 2048 + tt) * 64;
        vp[c] = h16(acc[mt][0][r] + gate * vep[c]);
        vp[16 + c] = h16(acc[mt][1][r] + gate * vep[16 + c]);
        vp[32 + c] = h16(acc[mt][2][r] + gate * vep[32 + c]);
        vp[48 + c] = h16(acc[mt][3][r] + gate * vep[48 + c]);
      }
    }
  }
}

// ---------------- bf16 GEMM, 64x128 tile: C = A(MxK) @ B(NxK)^T ----------------
__global__ __launch_bounds__(256) void gemm_bf16_64(
    const unsigned short* __restrict__ A, const unsigned short* __restrict__ B,
    float* __restrict__ C, int K, int ldc) {
  __shared__ unsigned short As[64 * 32];
  __shared__ unsigned short Bs[128 * 32];
  int bn = blockIdx.x, bm = blockIdx.y;
  int t = threadIdx.x;
  int w = t >> 6, lane = t & 63;
  int c = lane & 15, g = lane >> 4;
  int wm = w >> 1, wn = w & 1;

  f32x4 acc[2][4];
#pragma unroll
  for (int i = 0; i < 2; ++i)
#pragma unroll
    for (int j = 0; j < 4; ++j) acc[i][j] = (f32x4){0.f, 0.f, 0.f, 0.f};

  const unsigned short* Ab = A + (size_t)(bm * 64) * K;
  const unsigned short* Bb = B + (size_t)(bn * 128) * K;
  int srow = lane >> 2;
  int scol = (lane & 3) * 8;

  for (int k0 = 0; k0 < K; k0 += 32) {
    gl2lds16(Ab + (size_t)(w * 16 + srow) * K + k0 + scol, As + w * 512);
    gl2lds16(Bb + (size_t)(w * 16 + srow) * K + k0 + scol, Bs + w * 512);
    gl2lds16(Bb + (size_t)(64 + w * 16 + srow) * K + k0 + scol, Bs + 2048 + w * 512);
    __syncthreads();
    s16x8 af[2], bf[4];
#pragma unroll
    for (int mt = 0; mt < 2; ++mt)
      af[mt] = *(const s16x8*)(As + (wm * 32 + mt * 16 + c) * 32 + g * 8);
#pragma unroll
    for (int nt = 0; nt < 4; ++nt)
      bf[nt] = *(const s16x8*)(Bs + (wn * 64 + nt * 16 + c) * 32 + g * 8);
#pragma unroll
    for (int mt = 0; mt < 2; ++mt)
#pragma unroll
      for (int nt = 0; nt < 4; ++nt)
        acc[mt][nt] = __builtin_amdgcn_mfma_f32_16x16x32_bf16(af[mt], bf[nt], acc[mt][nt], 0, 0, 0);
    __syncthreads();
  }
#pragma unroll
  for (int mt = 0; mt < 2; ++mt)
#pragma unroll
    for (int nt = 0; nt < 4; ++nt)
#pragma unroll
      for (int r = 0; r < 4; ++r) {
        int rowg = bm * 64 + wm * 32 + mt * 16 + g * 4 + r;
        int colg = bn * 128 + wn * 64 + nt * 16 + c;
        C[(size_t)rowg * ldc + colg] = acc[mt][nt][r];
      }
}

// ---- V transpose to tiled layout: v_r[8][2048][64] -> v_p2[8][64 tiles][64 d][32 keys] ----
__global__ __launch_bounds__(256) void transpose_v(const unsigned short* __restrict__ v_r,
                                                   unsigned short* __restrict__ v_p2) {
  __shared__ unsigned short tile[64][72];
  int blk = blockIdx.x;
  int s = blk >> 5;
  int t0 = (blk & 31) * 64;
  int tt = threadIdx.x;
  int rcol = (tt & 7) * 8;
  int rrow = tt >> 3;
#pragma unroll
  for (int i = 0; i < 2; ++i) {
    int row = rrow + i * 32;
    *(s16x8*)&tile[row][rcol] = *(const s16x8*)(v_r + ((size_t)s * 2048 + t0 + row) * 64 + rcol);
  }
  __syncthreads();
#pragma unroll
  for (int i = 0; i < 2; ++i) {
    int idx = tt + i * 256;
    int ht = idx >> 8;
    int d = (idx >> 2) & 63;
    int e8 = (idx & 3) * 8;
    s16x8 o;
#pragma unroll
    for (int j = 0; j < 8; ++j) o[j] = tile[ht * 32 + e8 + j][d];
    *(s16x8*)(v_p2 + (size_t)s * 131072 + ((size_t)((t0 >> 5) + ht)) * 2048 + d * 32 + e8) = o;
  }
}

// ---------------- flash attention (R6 structure): S^T form, LDS-staged K/V ----------------
__global__ __launch_bounds__(256) void attn_kernel(
    const unsigned short* __restrict__ q_r, const unsigned short* __restrict__ k_r,
    const unsigned short* __restrict__ v_p2, unsigned short* __restrict__ y_b,
    const int* __restrict__ wptr) {
  const int W = *wptr;
  const int bid = blockIdx.x;
  const int qt = bid & 31, h = (bid >> 5) & 15, b = bid >> 9;
  const int tid = threadIdx.x;
  const int w = tid >> 6, lane = tid & 63, c = lane & 15, g = lane >> 4;
  const int r0b = qt * 64;
  const int r0w = r0b + w * 16;
  const int hkv = h >> 2;
  const float M = 11.5415603f;  // 8 * log2(e)

  __shared__ unsigned short Ks[32 * 68];
  __shared__ unsigned short Vs[64 * 40];

  const unsigned short* kbase = k_r + (size_t)(b * 4 + hkv) * 131072;
  const unsigned short* vbase = v_p2 + (size_t)(b * 4 + hkv) * 131072;
  const unsigned short* qbase = q_r + ((size_t)(b * 16 + h) * 2048 + r0w) * 64;

  s16x8 q_lo = *(const s16x8*)(qbase + c * 64 + g * 8);
  s16x8 q_hi = *(const s16x8*)(qbase + c * 64 + 32 + g * 8);

  int kt0w = r0w - W; if (kt0w < 0) kt0w = 0;
  const int ktEw = r0w + 16;
  int KT0 = r0b - W; if (KT0 < 0) KT0 = 0;
  KT0 &= ~31;
  const int KTE = r0b + 64;

  float l_part = 0.f;
  f32x4 acc[4];
#pragma unroll
  for (int dt = 0; dt < 4; ++dt) acc[dt] = (f32x4){0.f, 0.f, 0.f, 0.f};

  s16x8 pk = *(const s16x8*)(kbase + (size_t)KT0 * 64 + tid * 8);
  s16x8 pv = *(const s16x8*)(vbase + (size_t)(KT0 >> 5) * 2048 + tid * 8);

  unsigned short* kdst = Ks + (tid >> 3) * 68 + (tid & 7) * 8;
  unsigned short* vdst = Vs + (tid >> 2) * 40 + (tid & 3) * 8;

  for (int kt = KT0; kt < KTE; kt += 32) {
    int nkt = (kt + 32 < KTE) ? kt + 32 : kt;
    s16x8 nk = *(const s16x8*)(kbase + (size_t)nkt * 64 + tid * 8);
    s16x8 nv = *(const s16x8*)(vbase + (size_t)(nkt >> 5) * 2048 + tid * 8);

    *(s16x4*)kdst = __builtin_shufflevector(pk, pk, 0, 1, 2, 3);
    *(s16x4*)(kdst + 4) = __builtin_shufflevector(pk, pk, 4, 5, 6, 7);
    *(s16x8*)vdst = pv;
    __syncthreads();

    if (kt + 32 > kt0w && kt < ktEw) {
      const unsigned short* kr0 = Ks + c * 68 + g * 8;
      s16x4 a0 = *(const s16x4*)(kr0);
      s16x4 a1 = *(const s16x4*)(kr0 + 4);
      s16x4 a2 = *(const s16x4*)(kr0 + 32);
      s16x4 a3 = *(const s16x4*)(kr0 + 36);
      const unsigned short* kr1 = kr0 + 16 * 68;
      s16x4 a4 = *(const s16x4*)(kr1);
      s16x4 a5 = *(const s16x4*)(kr1 + 4);
      s16x4 a6 = *(const s16x4*)(kr1 + 32);
      s16x4 a7 = *(const s16x4*)(kr1 + 36);
      s16x8 k0lo = __builtin_shufflevector(a0, a1, 0, 1, 2, 3, 4, 5, 6, 7);
      s16x8 k0hi = __builtin_shufflevector(a2, a3, 0, 1, 2, 3, 4, 5, 6, 7);
      s16x8 k1lo = __builtin_shufflevector(a4, a5, 0, 1, 2, 3, 4, 5, 6, 7);
      s16x8 k1hi = __builtin_shufflevector(a6, a7, 0, 1, 2, 3, 4, 5, 6, 7);

      f32x4 S0 = (f32x4){0.f, 0.f, 0.f, 0.f};
      f32x4 S1 = (f32x4){0.f, 0.f, 0.f, 0.f};
      S0 = __builtin_amdgcn_mfma_f32_16x16x32_bf16(k0lo, q_lo, S0, 0, 0, 0);
      S0 = __builtin_amdgcn_mfma_f32_16x16x32_bf16(k0hi, q_hi, S0, 0, 0, 0);
      S1 = __builtin_amdgcn_mfma_f32_16x16x32_bf16(k1lo, q_lo, S1, 0, 0, 0);
      S1 = __builtin_amdgcn_mfma_f32_16x16x32_bf16(k1hi, q_hi, S1, 0, 0, 0);

      f16x4 P0, P1;
      const bool edge = (kt < kt0w + 32) || (kt + 32 > r0w);
      const int qrow = r0w + c;
#pragma unroll
      for (int r = 0; r < 4; ++r) {
        float p0 = fexp2(S0[r] - M);
        float p1 = fexp2(S1[r] - M);
        if (edge) {
          int k0i = kt + g * 4 + r;
          int k1i = k0i + 16;
          if (!(k0i <= qrow && k0i >= qrow - W)) p0 = 0.f;
          if (!(k1i <= qrow && k1i >= qrow - W)) p1 = 0.f;
        }
        l_part += p0 + p1;
        P0[r] = (_Float16)p0;
        P1[r] = (_Float16)p1;
      }

#pragma unroll
      for (int dt = 0; dt < 4; ++dt) {
        const unsigned short* vr = Vs + (dt * 16 + c) * 40 + g * 4;
        f16x4 va = *(const f16x4*)(vr);
        f16x4 vb = *(const f16x4*)(vr + 16);
        acc[dt] = __builtin_amdgcn_mfma_f32_16x16x16f16(va, P0, acc[dt], 0, 0, 0);
        acc[dt] = __builtin_amdgcn_mfma_f32_16x16x16f16(vb, P1, acc[dt], 0, 0, 0);
      }
    }
    __syncthreads();
    pk = nk; pv = nv;
  }

  float l = l_part;
  l += __shfl_xor(l, 16);
  l += __shfl_xor(l, 32);
  float inv = 1.0f / l;

  unsigned short* ob = y_b + ((size_t)(b * 2048 + r0w + c) * 16 + h) * 64 + g * 4;
#pragma unroll
  for (int dt = 0; dt < 4; ++dt) {
    ushort4 o;
    o.x = f2bf(acc[dt][0] * inv);
    o.y = f2bf(acc[dt][1] * inv);
    o.z = f2bf(acc[dt][2] * inv);
    o.w = f2bf(acc[dt][3] * inv);
    *(ushort4*)(ob + dt * 16) = o;
  }
}

extern "C" void kernel_launch(void* const* d_in, const int* in_sizes, int n_in,
                              void* d_out, int out_size, void* d_ws, size_t ws_size,
                              hipStream_t stream) {
  const float* x = (const float*)d_in[0];
  const float* ve = (const float*)d_in[1];
  const float* cosp = (const float*)d_in[2];
  const float* sinp = (const float*)d_in[3];
  const float* Wq = (const float*)d_in[4];
  const float* Wk = (const float*)d_in[5];
  const float* Wv = (const float*)d_in[6];
  const float* Wproj = (const float*)d_in[7];
  const float* Wgate = (const float*)d_in[8];
  const int* wptr = (const int*)d_in[9];

  unsigned short* xb = (unsigned short*)d_ws;        // 4096x1024 bf16
  unsigned short* wqkv = xb + 4194304;               // 1536x1024 bf16
  unsigned short* wpj = wqkv + 1572864;              // 1024x1024 bf16
  unsigned short* q_r = wpj + 1048576;               // [B,H,T,D] bf16
  unsigned short* k_r = q_r + 4194304;               // [B,Hkv,T,D] bf16
  unsigned short* v_r = k_r + 1048576;               // [B,Hkv,T,D] fp16
  unsigned short* y_b = v_r + 1048576;               // [B,T,H,D] bf16
  unsigned short* vp2 = y_b + 4194304;               // [B*Hkv][T/32][64][32] fp16 (2 MB)
  float* gatep = (float*)(vp2 + 1048576);            // [4096][4] fp32 (64 KB)

  cvt_gate<<<6720, 256, 0, stream>>>(x, Wq, Wk, Wv, Wproj, Wgate, xb, wqkv, wpj, gatep);
  gemm_qkv<<<dim3(12, 64), 256, 0, stream>>>(xb, wqkv, cosp, sinp, gatep, ve, q_r, k_r, v_r);
  transpose_v<<<256, 256, 0, stream>>>(v_r, vp2);
  attn_kernel<<<1024, 256, 0, stream>>>(q_r, k_r, vp2, y_b, wptr);
  gemm_bf16_64<<<dim3(8, 64), 256, 0, stream>>>(y_b, wpj, (float*)d_out, 1024, 1024);
}

// Round 10
// 173.023 us; speedup vs baseline: 1.1839x; 1.0737x over previous
//
#include <hip/hip_runtime.h>

// Shapes (fixed): B=2, T=2048, E=1024, H=16, Hkv=4, D=64, G=4, W=1024
// Scores bounded: q rmsnormed (|q|=8) * 0.125 * k rmsnormed (|k|=8) => |s| <= 8.
// log2(e) folded into q; softmax uses exp2 with FIXED max M = 8*log2(e).
// Attention: S^T = K·Q^T so P^T (C-layout) is directly the B-operand of
// mfma_f32_16x16x16f16 -> P never leaves registers. Double-buffered K/V LDS,
// ONE barrier per 32-key tile.
// GEMMs: BK=64, XOR-swizzled LDS columns (col ^ row&7) -> conflict-free reads
// while keeping global_load_lds's wave-uniform-base staging.

typedef float f32x4 __attribute__((ext_vector_type(4)));
typedef short s16x8 __attribute__((ext_vector_type(8)));
typedef short s16x4 __attribute__((ext_vector_type(4)));
typedef _Float16 f16x4 __attribute__((ext_vector_type(4)));

__device__ __forceinline__ unsigned short f2bf(float f) {
  unsigned u = __float_as_uint(f);
  u += 0x7fffu + ((u >> 16) & 1u);   // RNE
  return (unsigned short)(u >> 16);
}
__device__ __forceinline__ unsigned short h16(float f) {
  _Float16 h = (_Float16)f;
  return __builtin_bit_cast(unsigned short, h);
}

__device__ __forceinline__ float fexp2(float x) {
#if __has_builtin(__builtin_amdgcn_exp2f)
  return __builtin_amdgcn_exp2f(x);
#else
  return __expf(x * 0.69314718f);
#endif
}

// async global->LDS, 16B per lane; LDS dest = wave-uniform base + lane*16
__device__ __forceinline__ void gl2lds16(const unsigned short* g, unsigned short* l) {
  __builtin_amdgcn_global_load_lds((const __attribute__((address_space(1))) unsigned int*)g,
                                   (__attribute__((address_space(3))) unsigned int*)l, 16, 0, 0);
}

// ---------------- fp32->bf16 converts + gate, one launch ----------------
__global__ __launch_bounds__(256) void cvt_gate(
    const float* __restrict__ x, const float* __restrict__ wq, const float* __restrict__ wk,
    const float* __restrict__ wv, const float* __restrict__ wp, const float* __restrict__ wgate,
    unsigned short* __restrict__ xb, unsigned short* __restrict__ wqkv,
    unsigned short* __restrict__ wpj, float* __restrict__ gatep) {
  int blk = blockIdx.x;
  if (blk < 6656) {
    int i = blk * 256 + threadIdx.x;  // float4 index, total 1703936
    const float* s;
    unsigned short* d;
    if (i < 1048576) { s = x; d = xb; }
    else if (i < 1310720) { i -= 1048576; s = wq; d = wqkv; }
    else if (i < 1376256) { i -= 1310720; s = wk; d = wqkv + 1048576; }
    else if (i < 1441792) { i -= 1376256; s = wv; d = wqkv + 1310720; }
    else { i -= 1441792; s = wp; d = wpj; }
    float4 v = ((const float4*)s)[i];
    ushort4 o;
    o.x = f2bf(v.x); o.y = f2bf(v.y); o.z = f2bf(v.z); o.w = f2bf(v.w);
    ((ushort4*)d)[i] = o;
  } else {
    int i = (blk - 6656) * 256 + threadIdx.x;  // i = bt*4 + h, total 16384
    int bt = i >> 2, h = i & 3;
    const float4* xp = (const float4*)(x + (size_t)bt * 1024);
    const float4* wpt = (const float4*)(wgate + h * 32);
    float s = 0.f;
#pragma unroll
    for (int j = 0; j < 8; ++j) {
      float4 a = xp[j], b = wpt[j];
      s += a.x * b.x + a.y * b.y + a.z * b.z + a.w * b.w;
    }
    gatep[i] = 2.f / (1.f + __expf(-s));
  }
}

// ---- fused QKV GEMM (64x128 tile, BK=64, swizzled LDS) + RoPE/RMSNorm/gate-ve ----
// A = xb (4096x1024), B = wqkv (1536x1024). Col-tile bn: 0-7 q, 8-9 k, 10-11 v.
// v-epilogue writes vp2 tiled layout directly (transpose_v fused).
__global__ __launch_bounds__(256) void gemm_qkv(
    const unsigned short* __restrict__ A, const unsigned short* __restrict__ B,
    const float* __restrict__ cosp, const float* __restrict__ sinp,
    const float* __restrict__ gatep, const float* __restrict__ ve,
    unsigned short* __restrict__ q_r, unsigned short* __restrict__ k_r,
    unsigned short* __restrict__ vp2) {
  __shared__ unsigned short smem[12288];   // As 64x64 | Bs 128x64; epilogue aliases
  unsigned short* As = smem;               // 4096 elems
  unsigned short* Bs = smem + 4096;        // 8192 elems
  const int K = 1024;
  int bn = blockIdx.x, bm = blockIdx.y;
  int t = threadIdx.x;
  int w = t >> 6, lane = t & 63;
  int c = lane & 15, g = lane >> 4;
  int wm = w >> 1, wn = w & 1;

  f32x4 acc[2][4];
#pragma unroll
  for (int i = 0; i < 2; ++i)
#pragma unroll
    for (int j = 0; j < 4; ++j) acc[i][j] = (f32x4){0.f, 0.f, 0.f, 0.f};

  const unsigned short* Ab = A + (size_t)(bm * 64) * K;
  const unsigned short* Bb = B + (size_t)(bn * 128) * K;
  int srow = lane >> 3;                         // 0..7
  int ssw = ((lane & 7) ^ srow) * 8;            // swizzled source col group

  for (int k0 = 0; k0 < K; k0 += 64) {
#pragma unroll
    for (int j = 0; j < 2; ++j) {  // A rows w*16 .. +15
      int r = w * 16 + j * 8;
      gl2lds16(Ab + (size_t)(r + srow) * K + k0 + ssw, As + r * 64);
    }
#pragma unroll
    for (int j = 0; j < 4; ++j) {  // B rows w*32 .. +31
      int r = w * 32 + j * 8;
      gl2lds16(Bb + (size_t)(r + srow) * K + k0 + ssw, Bs + r * 64);
    }
    __syncthreads();
#pragma unroll
    for (int kk = 0; kk < 2; ++kk) {
      int sw = ((kk * 4 + g) ^ (c & 7)) * 8;  // row&7 == c&7 for all tiles
      s16x8 af[2], bf[4];
#pragma unroll
      for (int mt = 0; mt < 2; ++mt)
        af[mt] = *(const s16x8*)(As + (wm * 32 + mt * 16 + c) * 64 + sw);
#pragma unroll
      for (int nt = 0; nt < 4; ++nt)
        bf[nt] = *(const s16x8*)(Bs + (wn * 64 + nt * 16 + c) * 64 + sw);
#pragma unroll
      for (int mt = 0; mt < 2; ++mt)
#pragma unroll
        for (int nt = 0; nt < 4; ++nt)
          acc[mt][nt] = __builtin_amdgcn_mfma_f32_16x16x32_bf16(af[mt], bf[nt], acc[mt][nt], 0, 0, 0);
    }
    __syncthreads();
  }

  // epilogue: lane (c,g) reg r of (mt,nt): local row = wm*32+mt*16+g*4+r,
  // within-head d = nt*16 + c (head = 64 cols = wn half-tile)
  const float QSCL = 0.125f * 1.44269504f;
  if (bn < 10) {  // q/k: rope + rmsnorm -> wave-private LDS transpose -> b128 stores
    unsigned short* eb = smem + w * 2176;  // 32 x 68
#pragma unroll
    for (int mt = 0; mt < 2; ++mt) {
#pragma unroll
      for (int r = 0; r < 4; ++r) {
        int lrow = mt * 16 + g * 4 + r;
        int rowg = bm * 64 + wm * 32 + lrow;
        int tt = rowg & 2047;
        float v0 = acc[mt][0][r], v1 = acc[mt][1][r], v2 = acc[mt][2][r], v3 = acc[mt][3][r];
        float cs0 = cosp[tt * 32 + c], sn0 = sinp[tt * 32 + c];
        float cs1 = cosp[tt * 32 + 16 + c], sn1 = sinp[tt * 32 + 16 + c];
        float r0 = v0 * cs0 + v2 * sn0;
        float r1 = v1 * cs1 + v3 * sn1;
        float r2 = v2 * cs0 - v0 * sn0;
        float r3 = v3 * cs1 - v1 * sn1;
        float ss = r0 * r0 + r1 * r1 + r2 * r2 + r3 * r3;
        ss += __shfl_xor(ss, 1);
        ss += __shfl_xor(ss, 2);
        ss += __shfl_xor(ss, 4);
        ss += __shfl_xor(ss, 8);
        float sc = rsqrtf(ss * (1.0f / 64.0f) + 1.1920929e-07f);
        if (bn < 8) sc *= QSCL;
        eb[lrow * 68 + c] = f2bf(r0 * sc);
        eb[lrow * 68 + 16 + c] = f2bf(r1 * sc);
        eb[lrow * 68 + 32 + c] = f2bf(r2 * sc);
        eb[lrow * 68 + 48 + c] = f2bf(r3 * sc);
      }
    }
    asm volatile("s_waitcnt lgkmcnt(0)" ::: "memory");  // wave-private
#pragma unroll
    for (int j = 0; j < 4; ++j) {
      int idx = lane * 4 + j;  // 256 chunks: 32 rows x 8
      int lrow = idx >> 3;
      int ck = idx & 7;
      s16x8 val = *(const s16x8*)(eb + lrow * 68 + ck * 8);
      int rowg = bm * 64 + wm * 32 + lrow;
      int b = rowg >> 11, tt = rowg & 2047;
      unsigned short* dst;
      if (bn < 8) dst = q_r + ((size_t)(b * 16 + bn * 2 + wn) * 2048 + tt) * 64 + ck * 8;
      else dst = k_r + ((size_t)(b * 4 + (bn - 8) * 2 + wn) * 2048 + tt) * 64 + ck * 8;
      *(s16x8*)dst = val;
    }
  } else {  // v: + gate*ve, transpose to vp2 tiled [s][tile32][d][32keys] fp16
    unsigned short* eb = smem + w * 2560;  // 64 d x 40 (keys padded)
    int h = (bn - 10) * 2 + wn;
#pragma unroll
    for (int mt = 0; mt < 2; ++mt) {
#pragma unroll
      for (int r = 0; r < 4; ++r) {
        int key = mt * 16 + g * 4 + r;               // 0..31 within wave tile
        int rowg = bm * 64 + wm * 32 + key;
        float gate = gatep[rowg * 4 + h];
        const float* vep = ve + (size_t)rowg * 256 + h * 64;
        eb[(0 * 16 + c) * 40 + key] = h16(acc[mt][0][r] + gate * vep[c]);
        eb[(1 * 16 + c) * 40 + key] = h16(acc[mt][1][r] + gate * vep[16 + c]);
        eb[(2 * 16 + c) * 40 + key] = h16(acc[mt][2][r] + gate * vep[32 + c]);
        eb[(3 * 16 + c) * 40 + key] = h16(acc[mt][3][r] + gate * vep[48 + c]);
      }
    }
    asm volatile("s_waitcnt lgkmcnt(0)" ::: "memory");  // wave-private
    int rowg0 = bm * 64 + wm * 32;
    int b = rowg0 >> 11;
    int tile = (rowg0 & 2047) >> 5;
    unsigned short* vb = vp2 + ((size_t)(b * 4 + h) * 64 + tile) * 2048;
#pragma unroll
    for (int j = 0; j < 4; ++j) {
      int cid = j * 64 + lane;  // 256 chunks: 64 d x 4 keygroups
      int d = cid >> 2;
      int kg = cid & 3;
      s16x8 val = *(const s16x8*)(eb + d * 40 + kg * 8);
      *(s16x8*)(vb + d * 32 + kg * 8) = val;
    }
  }
}

// ---------------- bf16 GEMM 64x128, BK=64, swizzled: C = A @ B^T ----------------
__global__ __launch_bounds__(256) void gemm_bf16_64(
    const unsigned short* __restrict__ A, const unsigned short* __restrict__ B,
    float* __restrict__ C, int K, int ldc) {
  __shared__ unsigned short As[64 * 64];
  __shared__ unsigned short Bs[128 * 64];
  int bn = blockIdx.x, bm = blockIdx.y;
  int t = threadIdx.x;
  int w = t >> 6, lane = t & 63;
  int c = lane & 15, g = lane >> 4;
  int wm = w >> 1, wn = w & 1;

  f32x4 acc[2][4];
#pragma unroll
  for (int i = 0; i < 2; ++i)
#pragma unroll
    for (int j = 0; j < 4; ++j) acc[i][j] = (f32x4){0.f, 0.f, 0.f, 0.f};

  const unsigned short* Ab = A + (size_t)(bm * 64) * K;
  const unsigned short* Bb = B + (size_t)(bn * 128) * K;
  int srow = lane >> 3;
  int ssw = ((lane & 7) ^ srow) * 8;

  for (int k0 = 0; k0 < K; k0 += 64) {
#pragma unroll
    for (int j = 0; j < 2; ++j) {
      int r = w * 16 + j * 8;
      gl2lds16(Ab + (size_t)(r + srow) * K + k0 + ssw, As + r * 64);
    }
#pragma unroll
    for (int j = 0; j < 4; ++j) {
      int r = w * 32 + j * 8;
      gl2lds16(Bb + (size_t)(r + srow) * K + k0 + ssw, Bs + r * 64);
    }
    __syncthreads();
#pragma unroll
    for (int kk = 0; kk < 2; ++kk) {
      int sw = ((kk * 4 + g) ^ (c & 7)) * 8;
      s16x8 af[2], bf[4];
#pragma unroll
      for (int mt = 0; mt < 2; ++mt)
        af[mt] = *(const s16x8*)(As + (wm * 32 + mt * 16 + c) * 64 + sw);
#pragma unroll
      for (int nt = 0; nt < 4; ++nt)
        bf[nt] = *(const s16x8*)(Bs + (wn * 64 + nt * 16 + c) * 64 + sw);
#pragma unroll
      for (int mt = 0; mt < 2; ++mt)
#pragma unroll
        for (int nt = 0; nt < 4; ++nt)
          acc[mt][nt] = __builtin_amdgcn_mfma_f32_16x16x32_bf16(af[mt], bf[nt], acc[mt][nt], 0, 0, 0);
    }
    __syncthreads();
  }
#pragma unroll
  for (int mt = 0; mt < 2; ++mt)
#pragma unroll
    for (int nt = 0; nt < 4; ++nt)
#pragma unroll
      for (int r = 0; r < 4; ++r) {
        int rowg = bm * 64 + wm * 32 + mt * 16 + g * 4 + r;
        int colg = bn * 128 + wn * 64 + nt * 16 + c;
        C[(size_t)rowg * ldc + colg] = acc[mt][nt][r];
      }
}

// ---------------- flash attention: S^T form, dbuf LDS, ONE barrier/tile ----------------
__global__ __launch_bounds__(256) void attn_kernel(
    const unsigned short* __restrict__ q_r, const unsigned short* __restrict__ k_r,
    const unsigned short* __restrict__ v_p2, unsigned short* __restrict__ y_b,
    const int* __restrict__ wptr) {
  const int W = *wptr;
  const int bid = blockIdx.x;
  const int qt = bid & 31, h = (bid >> 5) & 15, b = bid >> 9;
  const int tid = threadIdx.x;
  const int w = tid >> 6, lane = tid & 63, c = lane & 15, g = lane >> 4;
  const int r0b = qt * 64;
  const int r0w = r0b + w * 16;
  const int hkv = h >> 2;
  const float M = 11.5415603f;  // 8 * log2(e)

  __shared__ unsigned short Ks[2][32 * 68];
  __shared__ unsigned short Vs[2][64 * 40];

  const unsigned short* kbase = k_r + (size_t)(b * 4 + hkv) * 131072;
  const unsigned short* vbase = v_p2 + (size_t)(b * 4 + hkv) * 131072;
  const unsigned short* qbase = q_r + ((size_t)(b * 16 + h) * 2048 + r0w) * 64;

  s16x8 q_lo = *(const s16x8*)(qbase + c * 64 + g * 8);
  s16x8 q_hi = *(const s16x8*)(qbase + c * 64 + 32 + g * 8);

  int kt0w = r0w - W; if (kt0w < 0) kt0w = 0;
  const int ktEw = r0w + 16;
  int KT0 = r0b - W; if (KT0 < 0) KT0 = 0;
  KT0 &= ~31;
  const int KTE = r0b + 64;

  float l_part = 0.f;
  f32x4 acc[4];
#pragma unroll
  for (int dt = 0; dt < 4; ++dt) acc[dt] = (f32x4){0.f, 0.f, 0.f, 0.f};

  s16x8 pk = *(const s16x8*)(kbase + (size_t)KT0 * 64 + tid * 8);
  s16x8 pv = *(const s16x8*)(vbase + (size_t)(KT0 >> 5) * 2048 + tid * 8);

  const int koff = (tid >> 3) * 68 + (tid & 7) * 8;
  const int voff = (tid >> 2) * 40 + (tid & 3) * 8;

  int bufI = 0;
  for (int kt = KT0; kt < KTE; kt += 32, bufI ^= 1) {
    int nkt = (kt + 32 < KTE) ? kt + 32 : kt;
    s16x8 nk = *(const s16x8*)(kbase + (size_t)nkt * 64 + tid * 8);
    s16x8 nv = *(const s16x8*)(vbase + (size_t)(nkt >> 5) * 2048 + tid * 8);

    // stage into buf bufI (other buffer may still be read by lagging waves - safe)
    unsigned short* kdst = &Ks[bufI][koff];
    *(s16x4*)kdst = __builtin_shufflevector(pk, pk, 0, 1, 2, 3);
    *(s16x4*)(kdst + 4) = __builtin_shufflevector(pk, pk, 4, 5, 6, 7);
    *(s16x8*)(&Vs[bufI][voff]) = pv;
    __syncthreads();  // the ONLY barrier per tile

    if (kt + 32 > kt0w && kt < ktEw) {
      const unsigned short* kr0 = &Ks[bufI][c * 68 + g * 8];
      s16x4 a0 = *(const s16x4*)(kr0);
      s16x4 a1 = *(const s16x4*)(kr0 + 4);
      s16x4 a2 = *(const s16x4*)(kr0 + 32);
      s16x4 a3 = *(const s16x4*)(kr0 + 36);
      const unsigned short* kr1 = kr0 + 16 * 68;
      s16x4 a4 = *(const s16x4*)(kr1);
      s16x4 a5 = *(const s16x4*)(kr1 + 4);
      s16x4 a6 = *(const s16x4*)(kr1 + 32);
      s16x4 a7 = *(const s16x4*)(kr1 + 36);
      s16x8 k0lo = __builtin_shufflevector(a0, a1, 0, 1, 2, 3, 4, 5, 6, 7);
      s16x8 k0hi = __builtin_shufflevector(a2, a3, 0, 1, 2, 3, 4, 5, 6, 7);
      s16x8 k1lo = __builtin_shufflevector(a4, a5, 0, 1, 2, 3, 4, 5, 6, 7);
      s16x8 k1hi = __builtin_shufflevector(a6, a7, 0, 1, 2, 3, 4, 5, 6, 7);

      f32x4 S0 = (f32x4){0.f, 0.f, 0.f, 0.f};
      f32x4 S1 = (f32x4){0.f, 0.f, 0.f, 0.f};
      S0 = __builtin_amdgcn_mfma_f32_16x16x32_bf16(k0lo, q_lo, S0, 0, 0, 0);
      S0 = __builtin_amdgcn_mfma_f32_16x16x32_bf16(k0hi, q_hi, S0, 0, 0, 0);
      S1 = __builtin_amdgcn_mfma_f32_16x16x32_bf16(k1lo, q_lo, S1, 0, 0, 0);
      S1 = __builtin_amdgcn_mfma_f32_16x16x32_bf16(k1hi, q_hi, S1, 0, 0, 0);

      f16x4 P0, P1;
      const bool edge = (kt < kt0w + 32) || (kt + 32 > r0w);
      const int qrow = r0w + c;
#pragma unroll
      for (int r = 0; r < 4; ++r) {
        float p0 = fexp2(S0[r] - M);
        float p1 = fexp2(S1[r] - M);
        if (edge) {
          int k0i = kt + g * 4 + r;
          int k1i = k0i + 16;
          if (!(k0i <= qrow && k0i >= qrow - W)) p0 = 0.f;
          if (!(k1i <= qrow && k1i >= qrow - W)) p1 = 0.f;
        }
        l_part += p0 + p1;
        P0[r] = (_Float16)p0;
        P1[r] = (_Float16)p1;
      }

#pragma unroll
      for (int dt = 0; dt < 4; ++dt) {
        const unsigned short* vr = &Vs[bufI][(dt * 16 + c) * 40 + g * 4];
        f16x4 va = *(const f16x4*)(vr);
        f16x4 vb = *(const f16x4*)(vr + 16);
        acc[dt] = __builtin_amdgcn_mfma_f32_16x16x16f16(va, P0, acc[dt], 0, 0, 0);
        acc[dt] = __builtin_amdgcn_mfma_f32_16x16x16f16(vb, P1, acc[dt], 0, 0, 0);
      }
    }
    pk = nk; pv = nv;
  }

  float l = l_part;
  l += __shfl_xor(l, 16);
  l += __shfl_xor(l, 32);
  float inv = 1.0f / l;

  unsigned short* ob = y_b + ((size_t)(b * 2048 + r0w + c) * 16 + h) * 64 + g * 4;
#pragma unroll
  for (int dt = 0; dt < 4; ++dt) {
    ushort4 o;
    o.x = f2bf(acc[dt][0] * inv);
    o.y = f2bf(acc[dt][1] * inv);
    o.z = f2bf(acc[dt][2] * inv);
    o.w = f2bf(acc[dt][3] * inv);
    *(ushort4*)(ob + dt * 16) = o;
  }
}

extern "C" void kernel_launch(void* const* d_in, const int* in_sizes, int n_in,
                              void* d_out, int out_size, void* d_ws, size_t ws_size,
                              hipStream_t stream) {
  const float* x = (const float*)d_in[0];
  const float* ve = (const float*)d_in[1];
  const float* cosp = (const float*)d_in[2];
  const float* sinp = (const float*)d_in[3];
  const float* Wq = (const float*)d_in[4];
  const float* Wk = (const float*)d_in[5];
  const float* Wv = (const float*)d_in[6];
  const float* Wproj = (const float*)d_in[7];
  const float* Wgate = (const float*)d_in[8];
  const int* wptr = (const int*)d_in[9];

  unsigned short* xb = (unsigned short*)d_ws;        // 4096x1024 bf16
  unsigned short* wqkv = xb + 4194304;               // 1536x1024 bf16
  unsigned short* wpj = wqkv + 1572864;              // 1024x1024 bf16
  unsigned short* q_r = wpj + 1048576;               // [B,H,T,D] bf16
  unsigned short* k_r = q_r + 4194304;               // [B,Hkv,T,D] bf16
  unsigned short* y_b = k_r + 1048576;               // [B,T,H,D] bf16
  unsigned short* vp2 = y_b + 4194304;               // [B*Hkv][T/32][64][32] fp16
  float* gatep = (float*)(vp2 + 1048576);            // [4096][4] fp32

  cvt_gate<<<6720, 256, 0, stream>>>(x, Wq, Wk, Wv, Wproj, Wgate, xb, wqkv, wpj, gatep);
  gemm_qkv<<<dim3(12, 64), 256, 0, stream>>>(xb, wqkv, cosp, sinp, gatep, ve, q_r, k_r, vp2);
  attn_kernel<<<1024, 256, 0, stream>>>(q_r, k_r, vp2, y_b, wptr);
  gemm_bf16_64<<<dim3(8, 64), 256, 0, stream>>>(y_b, wpj, (float*)d_out, 1024, 1024);
}